// Round 13
// baseline (168.240 us; speedup 1.0000x reference)
//
#include <hip/hip_runtime.h>

#define NEG_SLOPE 0.01f

using short8 = __attribute__((ext_vector_type(8))) short;
using f32x4  = __attribute__((ext_vector_type(4))) float;

__device__ inline float b2f(ushort u) {
    union { unsigned u; float f; } x; x.u = ((unsigned)u) << 16; return x.f;
}
__device__ inline ushort f2b(float f) {
    union { float f; unsigned u; } x; x.f = f;
    unsigned r = x.u + 0x7FFFu + ((x.u >> 16) & 1u);  // RNE
    return (ushort)(r >> 16);
}
__device__ inline void gload16(const void* g, void* l) {
    __builtin_amdgcn_global_load_lds((__attribute__((address_space(1))) void*)g,
                                     (__attribute__((address_space(3))) void*)l, 16, 0, 0);
}
__device__ inline int isroot(const int* __restrict__ batch, int d) {
    return (d == 0) || (batch[d] != batch[d - 1]);
}

// ---------------- E-pass 1: degree count + frontier1 + root pick (roots inline from batch) ----------------

__global__ void count_f1(const int* __restrict__ src, const int* __restrict__ dst,
                         const int* __restrict__ batch, int* __restrict__ cnt,
                         int* __restrict__ flag1, int* __restrict__ picked, int E, int N) {
    int i = blockIdx.x * blockDim.x + threadIdx.x;
    if (i < N && isroot(batch, i)) {
        picked[batch[i]] = i;
        flag1[i] = 1;   // roots are in S1
    }
    int e0 = i * 4;
    if (e0 + 3 < E) {
        int4 dq = *(const int4*)(dst + e0);
        int r0 = isroot(batch, dq.x), r1 = isroot(batch, dq.y);
        int r2 = isroot(batch, dq.z), r3 = isroot(batch, dq.w);
        atomicAdd(&cnt[dq.x], 1);
        atomicAdd(&cnt[dq.y], 1);
        atomicAdd(&cnt[dq.z], 1);
        atomicAdd(&cnt[dq.w], 1);
        if (r0 | r1 | r2 | r3) {
            int4 sq = *(const int4*)(src + e0);
            if (r0) flag1[sq.x] = 1;
            if (r1) flag1[sq.y] = 1;
            if (r2) flag1[sq.z] = 1;
            if (r3) flag1[sq.w] = 1;
        }
    } else if (e0 < E) {
        for (int e = e0; e < E; e++) {
            int d = dst[e];
            atomicAdd(&cnt[d], 1);
            if (isroot(batch, d)) flag1[src[e]] = 1;
        }
    }
}

// ---------------- E-pass 2: frontier2 (flag2 = S1 U {src : dst in S1}) ----------------

__global__ void frontier2v(const int* __restrict__ src, const int* __restrict__ dst,
                           const int* __restrict__ flag1, int* __restrict__ flag2,
                           int E, int N) {
    int i = blockIdx.x * blockDim.x + threadIdx.x;
    int e0 = i * 4;
    if (e0 + 3 < E) {
        int4 dq = *(const int4*)(dst + e0);
        int f0 = flag1[dq.x], f1 = flag1[dq.y], f2 = flag1[dq.z], f3 = flag1[dq.w];
        if (f0 | f1 | f2 | f3) {
            int4 sq = *(const int4*)(src + e0);
            if (f0) flag2[sq.x] = 1;
            if (f1) flag2[sq.y] = 1;
            if (f2) flag2[sq.z] = 1;
            if (f3) flag2[sq.w] = 1;
        }
    } else if (e0 < E) {
        for (int e = e0; e < E; e++) if (flag1[dst[e]]) flag2[src[e]] = 1;
    }
    if (i < N && flag1[i]) flag2[i] = 1;
}

// ---------------- single-kernel dual scan (all-predecessor wave-parallel lookback) ----------------
// Channels: (masked cnt, flag2). Fused: dis, rowptr/cur, pos2/list2, M2, W1t (transposed) + W2b (bf16 copy).
// Cross-block communication via device-scope atomics only (validated r11).

__global__ __launch_bounds__(256) void scan_dual(
    const int* __restrict__ cnt, const int* __restrict__ f2,
    int4* __restrict__ aggslot, float* __restrict__ dis,
    int* __restrict__ rowptr, int* __restrict__ cur,
    int* __restrict__ pos2, int* __restrict__ list2,
    int* __restrict__ counts, int N, int nb,
    const float* __restrict__ W1, ushort* __restrict__ W1t,
    const float* __restrict__ W2, ushort* __restrict__ W2b) {
    __shared__ int l0[256], l2[256];
    __shared__ int baseS[2];
    const int b = blockIdx.x, t = threadIdx.x;
    const int base = b * 1024 + t * 4;

    int c[4] = {0,0,0,0}, a2[4] = {0,0,0,0};
    if (base + 3 < N) {
        int4 q = *(const int4*)(cnt + base); c[0]=q.x; c[1]=q.y; c[2]=q.z; c[3]=q.w;
        int4 v = *(const int4*)(f2 + base);  a2[0]=v.x; a2[1]=v.y; a2[2]=v.z; a2[3]=v.w;
    } else {
        for (int i = 0; i < 4; i++) if (base + i < N) {
            c[i] = cnt[base + i]; a2[i] = f2[base + i];
        }
    }
#pragma unroll
    for (int i = 0; i < 4; i++)
        if (base + i < N) dis[base + i] = rsqrtf((float)c[i] + 1.0f);

    int m[4];
#pragma unroll
    for (int i = 0; i < 4; i++) m[i] = a2[i] ? c[i] : 0;
    int ts0 = m[0] + m[1] + m[2] + m[3];
    int ts2 = a2[0] + a2[1] + a2[2] + a2[3];
    l0[t] = ts0; l2[t] = ts2;
    __syncthreads();
    for (int off = 1; off < 256; off <<= 1) {
        int u0 = (t >= off) ? l0[t - off] : 0;
        int u2 = (t >= off) ? l2[t - off] : 0;
        __syncthreads();
        l0[t] += u0; l2[t] += u2;
        __syncthreads();
    }

    if (t == 0) {
        __hip_atomic_store(&aggslot[b].x, l0[255], __ATOMIC_RELAXED, __HIP_MEMORY_SCOPE_AGENT);
        __hip_atomic_store(&aggslot[b].y, l2[255], __ATOMIC_RELAXED, __HIP_MEMORY_SCOPE_AGENT);
        __hip_atomic_store(&aggslot[b].w, 1, __ATOMIC_RELEASE, __HIP_MEMORY_SCOPE_AGENT);
    }

    if (t < 64) {
        int g0 = 0, g2 = 0;
        for (int w0 = 0; w0 < b; w0 += 64) {
            int idx = w0 + t;
            if (idx < b) {
                while (__hip_atomic_load(&aggslot[idx].w, __ATOMIC_ACQUIRE,
                                         __HIP_MEMORY_SCOPE_AGENT) == 0) {
                    __builtin_amdgcn_s_sleep(1);
                }
                g0 += __hip_atomic_load(&aggslot[idx].x, __ATOMIC_RELAXED, __HIP_MEMORY_SCOPE_AGENT);
                g2 += __hip_atomic_load(&aggslot[idx].y, __ATOMIC_RELAXED, __HIP_MEMORY_SCOPE_AGENT);
            }
        }
#pragma unroll
        for (int s = 1; s < 64; s <<= 1) {
            g0 += __shfl_xor(g0, s, 64);
            g2 += __shfl_xor(g2, s, 64);
        }
        if (t == 0) { baseS[0] = g0; baseS[1] = g2; }
    }
    __syncthreads();

    int run0 = baseS[0] + l0[t] - ts0;
    int run2 = baseS[1] + l2[t] - ts2;
#pragma unroll
    for (int i = 0; i < 4; i++) {
        if (base + i < N) {
            rowptr[base + i] = run0;
            cur[base + i] = run0;
            if (a2[i]) { pos2[base + i] = run2; list2[run2] = base + i; }
        }
        run0 += m[i]; run2 += a2[i];
    }
    if (b == nb - 1 && t == 255) {
        counts[0] = baseS[1] + l2[255];   // M2
        rowptr[N] = baseS[0] + l0[255];   // total kept edges
    }

    // fused weight conversions: W1t transposed, W2b straight bf16 copy
    for (int idx = b * 256 + t; idx < 98304; idx += gridDim.x * 256) {
        if (idx < 32768) {                   // W1t[n][k] = W1[k][n], K=128
            int n = idx >> 7, k = idx & 127;
            W1t[idx] = f2b(W1[k * 256 + n]);
        } else {                             // W2b[idx] = bf16(W2[idx]), [k][col] layout
            int j = idx - 32768;
            W2b[j] = f2b(W2[j]);
        }
    }
}

// ---------------- E-pass 3: filtered CSR fill (only edges whose dst is in S2) ----------------

__global__ void fill_fv(const int* __restrict__ src, const int* __restrict__ dst,
                        const int* __restrict__ flag2, int* __restrict__ cur,
                        int* __restrict__ col, int E) {
    int i = blockIdx.x * blockDim.x + threadIdx.x;
    int e0 = i * 4;
    if (e0 + 3 < E) {
        int4 dq = *(const int4*)(dst + e0);
        int f0 = flag2[dq.x], f1 = flag2[dq.y], f2 = flag2[dq.z], f3 = flag2[dq.w];
        if (f0 | f1 | f2 | f3) {
            int4 sq = *(const int4*)(src + e0);
            if (f0) col[atomicAdd(&cur[dq.x], 1)] = sq.x;
            if (f1) col[atomicAdd(&cur[dq.y], 1)] = sq.y;
            if (f2) col[atomicAdd(&cur[dq.z], 1)] = sq.z;
            if (f3) col[atomicAdd(&cur[dq.w], 1)] = sq.w;
        }
    } else if (e0 < E) {
        for (int e = e0; e < E; e++) {
            int d = dst[e];
            if (flag2[d]) col[atomicAdd(&cur[d], 1)] = src[e];
        }
    }
}

// ---------------- layer-1 aggregation on S2 (compact): from f32 x directly ----------------

__global__ __launch_bounds__(256) void aggx_c(const float* __restrict__ x,
                                              const float* __restrict__ dis,
                                              const int* __restrict__ rowptr,
                                              const int* __restrict__ col,
                                              const int* __restrict__ list2,
                                              const int* __restrict__ counts,
                                              ushort* __restrict__ aggXc) {
    const int M2 = counts[0];
    int wave = blockIdx.x * 4 + (threadIdx.x >> 6);
    int lane = threadIdx.x & 63;
    int li = lane & 31, sub = lane >> 5;
    int stride = gridDim.x * 8;
    const float* xp = x + li * 4;
    for (int p = wave * 2 + sub; p < M2; p += stride) {
        int node = list2[p];
        float di = dis[node];
        float4 sv = *(const float4*)(xp + (size_t)node * 128);
        float a0 = di * sv.x, a1 = di * sv.y, a2 = di * sv.z, a3 = di * sv.w;
        int e = rowptr[node], e1 = rowptr[node + 1];
        for (; e + 2 <= e1; e += 2) {
            int s0 = col[e], s1 = col[e + 1];
            float w0 = dis[s0], w1 = dis[s1];
            float4 v0 = *(const float4*)(xp + (size_t)s0 * 128);
            float4 v1 = *(const float4*)(xp + (size_t)s1 * 128);
            a0 += w0 * v0.x + w1 * v1.x;
            a1 += w0 * v0.y + w1 * v1.y;
            a2 += w0 * v0.z + w1 * v1.z;
            a3 += w0 * v0.w + w1 * v1.w;
        }
        if (e < e1) {
            int s = col[e];
            float w = dis[s];
            float4 v = *(const float4*)(xp + (size_t)s * 128);
            a0 += w * v.x; a1 += w * v.y; a2 += w * v.z; a3 += w * v.w;
        }
        ushort4 o;
        o.x = f2b(di * a0); o.y = f2b(di * a1); o.z = f2b(di * a2); o.w = f2b(di * a3);
        *(ushort4*)(aggXc + (size_t)p * 128 + li * 4) = o;
    }
}

// ---------------- compact MFMA GEMM (layer 1): h1c = bf16( dis[list2[r]] * leaky(aggXc @ W1t^T + b1) ) ----------------

template <int K>
__global__ __launch_bounds__(512) void gemm_c(const ushort* __restrict__ A,
                                              const ushort* __restrict__ Bt,
                                              const float* __restrict__ bias,
                                              const float* __restrict__ dis,
                                              const int* __restrict__ list,
                                              const int* __restrict__ counts,
                                              ushort* __restrict__ C) {
    __shared__ ushort As[128 * 64];   // 16 KB
    __shared__ ushort Bs[256 * 64];   // 32 KB
    const int M = counts[0];
    const int t = threadIdx.x;
    const int lane = t & 63;
    const int w = t >> 6;
    const int wm = w >> 2, wn = w & 3;

    for (int tile = blockIdx.x; tile * 128 < M; tile += gridDim.x) {
        const int row0 = tile * 128;
        f32x4 acc[4][4] = {};

        for (int kt = 0; kt < K / 64; kt++) {
#pragma unroll
            for (int it = 0; it < 2; it++) {
                int q = it * 512 + t;
                int r = q >> 3, c = q & 7;
                int cs = c ^ (r & 7);
                int ga = min(row0 + r, M - 1);
                gload16(A + (size_t)ga * K + kt * 64 + cs * 8, &As[q * 8]);
            }
#pragma unroll
            for (int it = 0; it < 4; it++) {
                int q = it * 512 + t;
                int r = q >> 3, c = q & 7;
                int cs = c ^ (r & 7);
                gload16(Bt + (size_t)r * K + kt * 64 + cs * 8, &Bs[q * 8]);
            }
            __syncthreads();
#pragma unroll
            for (int ks = 0; ks < 2; ks++) {
                short8 a[4], b[4];
                int cc = ks * 4 + (lane >> 4);
#pragma unroll
                for (int m = 0; m < 4; m++) {
                    int R = wm * 64 + m * 16 + (lane & 15);
                    a[m] = *(const short8*)&As[R * 64 + ((cc ^ (R & 7)) * 8)];
                }
#pragma unroll
                for (int n = 0; n < 4; n++) {
                    int R = wn * 64 + n * 16 + (lane & 15);
                    b[n] = *(const short8*)&Bs[R * 64 + ((cc ^ (R & 7)) * 8)];
                }
#pragma unroll
                for (int m = 0; m < 4; m++)
#pragma unroll
                    for (int n = 0; n < 4; n++)
                        acc[m][n] = __builtin_amdgcn_mfma_f32_16x16x32_bf16(a[m], b[n], acc[m][n], 0, 0, 0);
            }
            __syncthreads();
        }

#pragma unroll
        for (int m = 0; m < 4; m++) {
#pragma unroll
            for (int j = 0; j < 4; j++) {
                int grow = row0 + wm * 64 + m * 16 + (lane >> 4) * 4 + j;
                if (grow >= M) continue;
                float dr = dis[list[grow]];
#pragma unroll
                for (int n = 0; n < 4; n++) {
                    int gcol = wn * 64 + n * 16 + (lane & 15);
                    float v = acc[m][n][j] + bias[gcol];
                    v = v > 0.f ? v : NEG_SLOPE * v;
                    C[(size_t)grow * 256 + gcol] = f2b(v * dr);
                }
            }
        }
    }
}

// ---------------- per-graph tail: layer-2 agg + W2 matvec + final W3 projection, no cross-block deps ----------------
// Block g handles graph g. s-nodes = {root} U N(root), processed in chunks of 8 sharing each W2 column load.

__global__ __launch_bounds__(256) void tail_g(
    const ushort* __restrict__ h1c, const float* __restrict__ dis,
    const int* __restrict__ rowptr, const int* __restrict__ col,
    const int* __restrict__ picked, const int* __restrict__ pos2,
    const ushort* __restrict__ W2b, const float* __restrict__ b2,
    const float* __restrict__ W3, const float* __restrict__ b3,
    float* __restrict__ out, int G) {
    __shared__ float aggs[8][256];
    __shared__ float sdis[8];
    __shared__ float vec[256];
    __shared__ float red[256];
    const int g = blockIdx.x;
    const int t = threadIdx.x;
    if (g >= G) return;
    const int i = picked[g];
    const float di = dis[i];
    const int re0 = rowptr[i];
    const int ns = rowptr[i + 1] - re0 + 1;  // self + neighbors
    float acc2 = 0.f;                         // col t of sum_s h2'[s]

    for (int c0 = 0; c0 < ns; c0 += 8) {
        int nc = min(8, ns - c0);
        // gather phase: agg1 rows for this s-chunk (f32, not rounded)
        for (int j = 0; j < nc; j++) {
            int sidx = c0 + j;
            int s = (sidx == 0) ? i : col[re0 + sidx - 1];
            float ds = dis[s];
            if (t == 0) sdis[j] = ds;
            const ushort* hp = h1c + t;
            float a = b2f(hp[(size_t)pos2[s] * 256]);
            int e = rowptr[s], e1 = rowptr[s + 1];
            for (; e + 4 <= e1; e += 4) {
                int u0 = col[e], u1 = col[e + 1], u2 = col[e + 2], u3 = col[e + 3];
                a += (b2f(hp[(size_t)pos2[u0] * 256]) + b2f(hp[(size_t)pos2[u1] * 256])) +
                     (b2f(hp[(size_t)pos2[u2] * 256]) + b2f(hp[(size_t)pos2[u3] * 256]));
            }
            for (; e < e1; e++) a += b2f(hp[(size_t)pos2[col[e]] * 256]);
            aggs[j][t] = ds * a;
        }
        __syncthreads();
        // matvec: 8 s-nodes share each W2 column load; p[j] static-indexed (rule #20)
        float p[8];
#pragma unroll
        for (int j = 0; j < 8; j++) p[j] = 0.f;
#pragma unroll 4
        for (int k = 0; k < 256; k++) {
            float wv = b2f(W2b[k * 256 + t]);
#pragma unroll
            for (int j = 0; j < 8; j++) p[j] += aggs[j][k] * wv;
        }
        float bb = b2[t];
#pragma unroll
        for (int j = 0; j < 8; j++) {
            if (j < nc) {
                float v = p[j] + bb;
                v = v > 0.f ? v : NEG_SLOPE * v;
                acc2 += sdis[j] * v;
            }
        }
        __syncthreads();   // protect aggs/sdis reuse in next chunk
    }

    // final projection: out[g] = (di*acc2) @ W3 + b3
    vec[t] = di * acc2;
    __syncthreads();
    int c = t & 15, seg = t >> 4;
    float pp = 0.f;
#pragma unroll
    for (int kk = 0; kk < 16; kk++) {
        int k = seg * 16 + kk;
        pp += vec[k] * W3[k * 16 + c];
    }
    red[t] = pp;
    __syncthreads();
    if (t < 16) {
        float s = 0.f;
#pragma unroll
        for (int ss = 0; ss < 16; ss++) s += red[ss * 16 + t];
        out[g * 16 + t] = s + b3[t];
    }
}

// ---------------- launch ----------------

extern "C" void kernel_launch(void* const* d_in, const int* in_sizes, int n_in,
                              void* d_out, int out_size, void* d_ws, size_t ws_size,
                              hipStream_t stream) {
    const float* x   = (const float*)d_in[0];
    const int* ei    = (const int*)d_in[1];
    const int* batch = (const int*)d_in[2];
    const float* W1  = (const float*)d_in[3];
    const float* b1  = (const float*)d_in[4];
    const float* W2  = (const float*)d_in[5];
    const float* b2  = (const float*)d_in[6];
    const float* W3  = (const float*)d_in[7];
    const float* b3  = (const float*)d_in[8];

    const int IN = 128, H = 256, OUT = 16;
    int N = in_sizes[0] / IN;
    int E = in_sizes[1] / 2;
    int G = out_size / OUT;
    const int* srcp = ei;
    const int* dstp = ei + E;

    char* p = (char*)d_ws;
    auto carve = [&](size_t bytes) {
        char* q = p;
        p += (bytes + 255) & ~(size_t)255;
        return q;
    };
    // contiguous zeroed region: cnt | flag1 | flag2 | aggslot
    int*    cnt    = (int*)carve((size_t)N * 4);
    int*    flag1  = (int*)carve((size_t)N * 4);
    int*    flag2  = (int*)carve((size_t)N * 4);
    int4*   aggslot= (int4*)carve(1024 * 16);
    char*   zend   = p;
    float*  dis    = (float*)carve((size_t)N * 4);
    int*    rowptr = (int*)carve(((size_t)N + 1) * 4);
    int*    cur    = (int*)carve((size_t)N * 4);
    int*    counts = (int*)carve(256);
    int*    picked = (int*)carve((size_t)G * 4);
    int*    pos2   = (int*)carve((size_t)N * 4);
    int*    list2  = (int*)carve((size_t)N * 4);
    int*    col    = (int*)carve((size_t)E * 4);
    ushort* W1t    = (ushort*)carve((size_t)256 * 128 * 2);
    ushort* W2b    = (ushort*)carve((size_t)256 * 256 * 2);
    ushort* aggXc  = (ushort*)carve((size_t)N * 128 * 2);  // [M2][128]
    ushort* h1c    = (ushort*)carve((size_t)N * H * 2);    // [M2][256]

    int nb = (N + 1023) / 1024;
    int e4 = (E + 3) / 4;
    int epN = (e4 > N ? e4 : N);

    // 1) zero counters/flags/slots
    hipMemsetAsync(cnt, 0, (size_t)(zend - (char*)cnt), stream);
    // 2) degrees + frontier1 + root pick
    count_f1<<<(epN + 255) / 256, 256, 0, stream>>>(srcp, dstp, batch, cnt, flag1, picked, E, N);
    // 3) frontier2
    frontier2v<<<(epN + 255) / 256, 256, 0, stream>>>(srcp, dstp, flag1, flag2, E, N);
    // 4) single-kernel dual scan (+dis +weights)
    scan_dual<<<nb, 256, 0, stream>>>(cnt, flag2, aggslot, dis, rowptr, cur,
                                      pos2, list2, counts, N, nb, W1, W1t, W2, W2b);
    // 5) filtered CSR fill
    fill_fv<<<(e4 + 255) / 256, 256, 0, stream>>>(srcp, dstp, flag2, cur, col, E);
    // 6) layer-1 aggregation on S2
    aggx_c<<<1024, 256, 0, stream>>>(x, dis, rowptr, col, list2, counts, aggXc);
    // 7) layer-1 GEMM -> h1c
    gemm_c<128><<<64, 512, 0, stream>>>(aggXc, W1t, b1, dis, list2, counts, h1c);
    // 8) per-graph tail: layer-2 + final
    tail_g<<<G, 256, 0, stream>>>(h1c, dis, rowptr, col, picked, pos2, W2b, b2,
                                  W3, b3, (float*)d_out, G);
}

// Round 14
// 134.418 us; speedup vs baseline: 1.2516x; 1.2516x over previous
//
#include <hip/hip_runtime.h>

#define NEG_SLOPE 0.01f

using short8 = __attribute__((ext_vector_type(8))) short;
using f32x4  = __attribute__((ext_vector_type(4))) float;

__device__ inline float b2f(ushort u) {
    union { unsigned u; float f; } x; x.u = ((unsigned)u) << 16; return x.f;
}
__device__ inline ushort f2b(float f) {
    union { float f; unsigned u; } x; x.f = f;
    unsigned r = x.u + 0x7FFFu + ((x.u >> 16) & 1u);  // RNE
    return (ushort)(r >> 16);
}
__device__ inline void gload16(const void* g, void* l) {
    __builtin_amdgcn_global_load_lds((__attribute__((address_space(1))) void*)g,
                                     (__attribute__((address_space(3))) void*)l, 16, 0, 0);
}
__device__ inline int isroot(const int* __restrict__ batch, int d) {
    return (d == 0) || (batch[d] != batch[d - 1]);
}

// ---------------- E-pass 1: degree count + frontier1 + root pick (roots inline from batch) ----------------

__global__ void count_f1(const int* __restrict__ src, const int* __restrict__ dst,
                         const int* __restrict__ batch, int* __restrict__ cnt,
                         int* __restrict__ flag1, int* __restrict__ picked, int E, int N) {
    int i = blockIdx.x * blockDim.x + threadIdx.x;
    if (i < N && isroot(batch, i)) {
        picked[batch[i]] = i;
        flag1[i] = 1;   // roots are in S1
    }
    int e0 = i * 4;
    if (e0 + 3 < E) {
        int4 dq = *(const int4*)(dst + e0);
        int r0 = isroot(batch, dq.x), r1 = isroot(batch, dq.y);
        int r2 = isroot(batch, dq.z), r3 = isroot(batch, dq.w);
        atomicAdd(&cnt[dq.x], 1);
        atomicAdd(&cnt[dq.y], 1);
        atomicAdd(&cnt[dq.z], 1);
        atomicAdd(&cnt[dq.w], 1);
        if (r0 | r1 | r2 | r3) {
            int4 sq = *(const int4*)(src + e0);
            if (r0) flag1[sq.x] = 1;
            if (r1) flag1[sq.y] = 1;
            if (r2) flag1[sq.z] = 1;
            if (r3) flag1[sq.w] = 1;
        }
    } else if (e0 < E) {
        for (int e = e0; e < E; e++) {
            int d = dst[e];
            atomicAdd(&cnt[d], 1);
            if (isroot(batch, d)) flag1[src[e]] = 1;
        }
    }
}

// ---------------- E-pass 2: frontier2 (flag2 = S1 U {src : dst in S1}) ----------------

__global__ void frontier2v(const int* __restrict__ src, const int* __restrict__ dst,
                           const int* __restrict__ flag1, int* __restrict__ flag2,
                           int E, int N) {
    int i = blockIdx.x * blockDim.x + threadIdx.x;
    int e0 = i * 4;
    if (e0 + 3 < E) {
        int4 dq = *(const int4*)(dst + e0);
        int f0 = flag1[dq.x], f1 = flag1[dq.y], f2 = flag1[dq.z], f3 = flag1[dq.w];
        if (f0 | f1 | f2 | f3) {
            int4 sq = *(const int4*)(src + e0);
            if (f0) flag2[sq.x] = 1;
            if (f1) flag2[sq.y] = 1;
            if (f2) flag2[sq.z] = 1;
            if (f3) flag2[sq.w] = 1;
        }
    } else if (e0 < E) {
        for (int e = e0; e < E; e++) if (flag1[dst[e]]) flag2[src[e]] = 1;
    }
    if (i < N && flag1[i]) flag2[i] = 1;
}

// ---------------- single-kernel triple scan (all-predecessor wave-parallel lookback) ----------------
// Channels: (masked cnt, flag1, flag2). Fused: dis, rowptr/cur, pos1/2, list1/2, counts, wtrans.
// Cross-block communication ONLY via device-scope atomics (validated r11; bulk data never crosses).

__global__ __launch_bounds__(256) void scan_one(
    const int* __restrict__ cnt, const int* __restrict__ f1, const int* __restrict__ f2,
    int4* __restrict__ aggslot, float* __restrict__ dis,
    int* __restrict__ rowptr, int* __restrict__ cur,
    int* __restrict__ pos1, int* __restrict__ pos2,
    int* __restrict__ list1, int* __restrict__ list2,
    int* __restrict__ counts, int N, int nb,
    const float* __restrict__ W1, ushort* __restrict__ W1t,
    const float* __restrict__ W2, ushort* __restrict__ W2t) {
    __shared__ int l0[256], l1[256], l2[256];
    __shared__ int baseS[3];
    const int b = blockIdx.x, t = threadIdx.x;
    const int base = b * 1024 + t * 4;

    int c[4] = {0,0,0,0}, a1[4] = {0,0,0,0}, a2[4] = {0,0,0,0};
    if (base + 3 < N) {
        int4 q = *(const int4*)(cnt + base); c[0]=q.x; c[1]=q.y; c[2]=q.z; c[3]=q.w;
        int4 u = *(const int4*)(f1 + base);  a1[0]=u.x; a1[1]=u.y; a1[2]=u.z; a1[3]=u.w;
        int4 v = *(const int4*)(f2 + base);  a2[0]=v.x; a2[1]=v.y; a2[2]=v.z; a2[3]=v.w;
    } else {
        for (int i = 0; i < 4; i++) if (base + i < N) {
            c[i] = cnt[base + i]; a1[i] = f1[base + i]; a2[i] = f2[base + i];
        }
    }
#pragma unroll
    for (int i = 0; i < 4; i++)
        if (base + i < N) dis[base + i] = rsqrtf((float)c[i] + 1.0f);

    int m[4];
#pragma unroll
    for (int i = 0; i < 4; i++) m[i] = a2[i] ? c[i] : 0;
    int ts0 = m[0] + m[1] + m[2] + m[3];
    int ts1 = a1[0] + a1[1] + a1[2] + a1[3];
    int ts2 = a2[0] + a2[1] + a2[2] + a2[3];
    l0[t] = ts0; l1[t] = ts1; l2[t] = ts2;
    __syncthreads();
    for (int off = 1; off < 256; off <<= 1) {
        int u0 = (t >= off) ? l0[t - off] : 0;
        int u1 = (t >= off) ? l1[t - off] : 0;
        int u2 = (t >= off) ? l2[t - off] : 0;
        __syncthreads();
        l0[t] += u0; l1[t] += u1; l2[t] += u2;
        __syncthreads();
    }

    if (t == 0) {
        __hip_atomic_store(&aggslot[b].x, l0[255], __ATOMIC_RELAXED, __HIP_MEMORY_SCOPE_AGENT);
        __hip_atomic_store(&aggslot[b].y, l1[255], __ATOMIC_RELAXED, __HIP_MEMORY_SCOPE_AGENT);
        __hip_atomic_store(&aggslot[b].z, l2[255], __ATOMIC_RELAXED, __HIP_MEMORY_SCOPE_AGENT);
        __hip_atomic_store(&aggslot[b].w, 1, __ATOMIC_RELEASE, __HIP_MEMORY_SCOPE_AGENT);
    }

    if (t < 64) {
        int g0 = 0, g1 = 0, g2 = 0;
        for (int w0 = 0; w0 < b; w0 += 64) {
            int idx = w0 + t;
            if (idx < b) {
                while (__hip_atomic_load(&aggslot[idx].w, __ATOMIC_ACQUIRE,
                                         __HIP_MEMORY_SCOPE_AGENT) == 0) {
                    __builtin_amdgcn_s_sleep(1);
                }
                g0 += __hip_atomic_load(&aggslot[idx].x, __ATOMIC_RELAXED, __HIP_MEMORY_SCOPE_AGENT);
                g1 += __hip_atomic_load(&aggslot[idx].y, __ATOMIC_RELAXED, __HIP_MEMORY_SCOPE_AGENT);
                g2 += __hip_atomic_load(&aggslot[idx].z, __ATOMIC_RELAXED, __HIP_MEMORY_SCOPE_AGENT);
            }
        }
#pragma unroll
        for (int s = 1; s < 64; s <<= 1) {
            g0 += __shfl_xor(g0, s, 64);
            g1 += __shfl_xor(g1, s, 64);
            g2 += __shfl_xor(g2, s, 64);
        }
        if (t == 0) { baseS[0] = g0; baseS[1] = g1; baseS[2] = g2; }
    }
    __syncthreads();

    int run0 = baseS[0] + l0[t] - ts0;
    int run1 = baseS[1] + l1[t] - ts1;
    int run2 = baseS[2] + l2[t] - ts2;
#pragma unroll
    for (int i = 0; i < 4; i++) {
        if (base + i < N) {
            rowptr[base + i] = run0;
            cur[base + i] = run0;
            if (a1[i]) { pos1[base + i] = run1; list1[run1] = base + i; }
            if (a2[i]) { pos2[base + i] = run2; list2[run2] = base + i; }
        }
        run0 += m[i]; run1 += a1[i]; run2 += a2[i];
    }
    if (b == nb - 1 && t == 255) {
        counts[0] = baseS[1] + l1[255];   // M1
        counts[1] = baseS[2] + l2[255];   // M2
        rowptr[N] = baseS[0] + l0[255];   // total kept edges
    }

    // fused weight transposes
    for (int idx = b * 256 + t; idx < 98304; idx += gridDim.x * 256) {
        if (idx < 32768) {                   // W1t[n][k] = W1[k][n], K=128
            int n = idx >> 7, k = idx & 127;
            W1t[idx] = f2b(W1[k * 256 + n]);
        } else {                             // W2t[n][k] = W2[k][n], K=256
            int j = idx - 32768;
            int n = j >> 8, k = j & 255;
            W2t[j] = f2b(W2[k * 256 + n]);
        }
    }
}

// ---------------- E-pass 3: filtered CSR fill (only edges whose dst is in S2) ----------------

__global__ void fill_fv(const int* __restrict__ src, const int* __restrict__ dst,
                        const int* __restrict__ flag2, int* __restrict__ cur,
                        int* __restrict__ col, int E) {
    int i = blockIdx.x * blockDim.x + threadIdx.x;
    int e0 = i * 4;
    if (e0 + 3 < E) {
        int4 dq = *(const int4*)(dst + e0);
        int f0 = flag2[dq.x], f1 = flag2[dq.y], f2 = flag2[dq.z], f3 = flag2[dq.w];
        if (f0 | f1 | f2 | f3) {
            int4 sq = *(const int4*)(src + e0);
            if (f0) col[atomicAdd(&cur[dq.x], 1)] = sq.x;
            if (f1) col[atomicAdd(&cur[dq.y], 1)] = sq.y;
            if (f2) col[atomicAdd(&cur[dq.z], 1)] = sq.z;
            if (f3) col[atomicAdd(&cur[dq.w], 1)] = sq.w;
        }
    } else if (e0 < E) {
        for (int e = e0; e < E; e++) {
            int d = dst[e];
            if (flag2[d]) col[atomicAdd(&cur[d], 1)] = src[e];
        }
    }
}

// ---------------- layer-1 aggregation on S2 (compact): from f32 x directly ----------------

__global__ __launch_bounds__(256) void aggx_c(const float* __restrict__ x,
                                              const float* __restrict__ dis,
                                              const int* __restrict__ rowptr,
                                              const int* __restrict__ col,
                                              const int* __restrict__ list2,
                                              const int* __restrict__ counts,
                                              ushort* __restrict__ aggXc) {
    const int M2 = counts[1];
    int wave = blockIdx.x * 4 + (threadIdx.x >> 6);
    int lane = threadIdx.x & 63;
    int li = lane & 31, sub = lane >> 5;
    int stride = gridDim.x * 8;
    const float* xp = x + li * 4;
    for (int p = wave * 2 + sub; p < M2; p += stride) {
        int node = list2[p];
        float di = dis[node];
        float4 sv = *(const float4*)(xp + (size_t)node * 128);
        float a0 = di * sv.x, a1 = di * sv.y, a2 = di * sv.z, a3 = di * sv.w;
        int e = rowptr[node], e1 = rowptr[node + 1];
        for (; e + 2 <= e1; e += 2) {
            int s0 = col[e], s1 = col[e + 1];
            float w0 = dis[s0], w1 = dis[s1];
            float4 v0 = *(const float4*)(xp + (size_t)s0 * 128);
            float4 v1 = *(const float4*)(xp + (size_t)s1 * 128);
            a0 += w0 * v0.x + w1 * v1.x;
            a1 += w0 * v0.y + w1 * v1.y;
            a2 += w0 * v0.z + w1 * v1.z;
            a3 += w0 * v0.w + w1 * v1.w;
        }
        if (e < e1) {
            int s = col[e];
            float w = dis[s];
            float4 v = *(const float4*)(xp + (size_t)s * 128);
            a0 += w * v.x; a1 += w * v.y; a2 += w * v.z; a3 += w * v.w;
        }
        ushort4 o;
        o.x = f2b(di * a0); o.y = f2b(di * a1); o.z = f2b(di * a2); o.w = f2b(di * a3);
        *(ushort4*)(aggXc + (size_t)p * 128 + li * 4) = o;
    }
}

// ---------------- layer-2 aggregation on S1 (compact), h1c indexed via pos2 ----------------

__global__ __launch_bounds__(256) void agg2_c(const ushort* __restrict__ h1c,
                                              const float* __restrict__ dis,
                                              const int* __restrict__ rowptr,
                                              const int* __restrict__ col,
                                              const int* __restrict__ list1,
                                              const int* __restrict__ pos2,
                                              const int* __restrict__ counts,
                                              ushort* __restrict__ agg1c) {
    const int M1 = counts[0];
    int wave = blockIdx.x * 4 + (threadIdx.x >> 6);
    int lane = threadIdx.x & 63;
    int li = lane & 31, sub = lane >> 5;
    int stride = gridDim.x * 8;
    const ushort* hp = h1c + (size_t)li * 8;
    for (int p = wave * 2 + sub; p < M1; p += stride) {
        int i = list1[p];
        float di = dis[i];
        float a[8];
        {
            short8 v = *(const short8*)(hp + (size_t)pos2[i] * 256);
#pragma unroll
            for (int j = 0; j < 8; j++) a[j] = b2f((ushort)v[j]);
        }
        int e1 = rowptr[i + 1];
        for (int e = rowptr[i]; e < e1; e++) {
            short8 v = *(const short8*)(hp + (size_t)pos2[col[e]] * 256);
#pragma unroll
            for (int j = 0; j < 8; j++) a[j] += b2f((ushort)v[j]);
        }
        short8 o;
#pragma unroll
        for (int j = 0; j < 8; j++) o[j] = (short)f2b(di * a[j]);
        *(short8*)(agg1c + (size_t)p * 256 + li * 8) = o;
    }
}

// ---------------- compact MFMA GEMM: C[M x 256] = bf16( dis[list[row]] * leaky(A @ Bt^T + bias) ) ----------------

template <int K>
__global__ __launch_bounds__(512) void gemm_c(const ushort* __restrict__ A,
                                              const ushort* __restrict__ Bt,
                                              const float* __restrict__ bias,
                                              const float* __restrict__ dis,
                                              const int* __restrict__ list,
                                              const int* __restrict__ counts, int which,
                                              ushort* __restrict__ C) {
    __shared__ ushort As[128 * 64];   // 16 KB
    __shared__ ushort Bs[256 * 64];   // 32 KB
    const int M = counts[which];
    const int t = threadIdx.x;
    const int lane = t & 63;
    const int w = t >> 6;
    const int wm = w >> 2, wn = w & 3;

    for (int tile = blockIdx.x; tile * 128 < M; tile += gridDim.x) {
        const int row0 = tile * 128;
        f32x4 acc[4][4] = {};

        for (int kt = 0; kt < K / 64; kt++) {
#pragma unroll
            for (int it = 0; it < 2; it++) {
                int q = it * 512 + t;
                int r = q >> 3, c = q & 7;
                int cs = c ^ (r & 7);
                int ga = min(row0 + r, M - 1);
                gload16(A + (size_t)ga * K + kt * 64 + cs * 8, &As[q * 8]);
            }
#pragma unroll
            for (int it = 0; it < 4; it++) {
                int q = it * 512 + t;
                int r = q >> 3, c = q & 7;
                int cs = c ^ (r & 7);
                gload16(Bt + (size_t)r * K + kt * 64 + cs * 8, &Bs[q * 8]);
            }
            __syncthreads();
#pragma unroll
            for (int ks = 0; ks < 2; ks++) {
                short8 a[4], b[4];
                int cc = ks * 4 + (lane >> 4);
#pragma unroll
                for (int m = 0; m < 4; m++) {
                    int R = wm * 64 + m * 16 + (lane & 15);
                    a[m] = *(const short8*)&As[R * 64 + ((cc ^ (R & 7)) * 8)];
                }
#pragma unroll
                for (int n = 0; n < 4; n++) {
                    int R = wn * 64 + n * 16 + (lane & 15);
                    b[n] = *(const short8*)&Bs[R * 64 + ((cc ^ (R & 7)) * 8)];
                }
#pragma unroll
                for (int m = 0; m < 4; m++)
#pragma unroll
                    for (int n = 0; n < 4; n++)
                        acc[m][n] = __builtin_amdgcn_mfma_f32_16x16x32_bf16(a[m], b[n], acc[m][n], 0, 0, 0);
            }
            __syncthreads();
        }

#pragma unroll
        for (int m = 0; m < 4; m++) {
#pragma unroll
            for (int j = 0; j < 4; j++) {
                int grow = row0 + wm * 64 + m * 16 + (lane >> 4) * 4 + j;
                if (grow >= M) continue;
                float dr = dis[list[grow]];
#pragma unroll
                for (int n = 0; n < 4; n++) {
                    int gcol = wn * 64 + n * 16 + (lane & 15);
                    float v = acc[m][n][j] + bias[gcol];
                    v = v > 0.f ? v : NEG_SLOPE * v;
                    C[(size_t)grow * 256 + gcol] = f2b(v * dr);
                }
            }
        }
    }
}

// ---------------- final: per graph, aggregate h2c at the root (via pos1), then 256x16 GEMM ----------------

__global__ __launch_bounds__(256) void final_c(const ushort* __restrict__ h2c,
                                               const float* __restrict__ dis,
                                               const int* __restrict__ rowptr,
                                               const int* __restrict__ col,
                                               const int* __restrict__ picked,
                                               const int* __restrict__ pos1,
                                               const float* __restrict__ W3,
                                               const float* __restrict__ b3,
                                               float* __restrict__ out, int G) {
    __shared__ float agg[256];
    __shared__ float red[256];
    int g = blockIdx.x;
    int t = threadIdx.x;
    if (g >= G) return;
    int i = picked[g];
    float di = dis[i];
    float a = b2f(h2c[(size_t)pos1[i] * 256 + t]);
    int e1 = rowptr[i + 1];
    for (int e = rowptr[i]; e < e1; e++) {
        a += b2f(h2c[(size_t)pos1[col[e]] * 256 + t]);
    }
    agg[t] = di * a;
    __syncthreads();
    int c = t & 15, seg = t >> 4;
    float p = 0.f;
#pragma unroll
    for (int kk = 0; kk < 16; kk++) {
        int k = seg * 16 + kk;
        p += agg[k] * W3[k * 16 + c];
    }
    red[t] = p;
    __syncthreads();
    if (t < 16) {
        float sres = 0.f;
#pragma unroll
        for (int ss = 0; ss < 16; ss++) sres += red[ss * 16 + t];
        out[g * 16 + t] = sres + b3[t];
    }
}

// ---------------- launch ----------------

extern "C" void kernel_launch(void* const* d_in, const int* in_sizes, int n_in,
                              void* d_out, int out_size, void* d_ws, size_t ws_size,
                              hipStream_t stream) {
    const float* x   = (const float*)d_in[0];
    const int* ei    = (const int*)d_in[1];
    const int* batch = (const int*)d_in[2];
    const float* W1  = (const float*)d_in[3];
    const float* b1  = (const float*)d_in[4];
    const float* W2  = (const float*)d_in[5];
    const float* b2  = (const float*)d_in[6];
    const float* W3  = (const float*)d_in[7];
    const float* b3  = (const float*)d_in[8];

    const int IN = 128, H = 256, OUT = 16;
    int N = in_sizes[0] / IN;
    int E = in_sizes[1] / 2;
    int G = out_size / OUT;
    const int* srcp = ei;
    const int* dstp = ei + E;

    char* p = (char*)d_ws;
    auto carve = [&](size_t bytes) {
        char* q = p;
        p += (bytes + 255) & ~(size_t)255;
        return q;
    };
    // contiguous zeroed region: cnt | flag1 | flag2 | aggslot
    int*    cnt    = (int*)carve((size_t)N * 4);
    int*    flag1  = (int*)carve((size_t)N * 4);
    int*    flag2  = (int*)carve((size_t)N * 4);
    int4*   aggslot= (int4*)carve(1024 * 16);
    char*   zend   = p;
    float*  dis    = (float*)carve((size_t)N * 4);
    int*    rowptr = (int*)carve(((size_t)N + 1) * 4);
    int*    cur    = (int*)carve((size_t)N * 4);
    int*    counts = (int*)carve(256);
    int*    picked = (int*)carve((size_t)G * 4);
    int*    pos1   = (int*)carve((size_t)N * 4);
    int*    pos2   = (int*)carve((size_t)N * 4);
    int*    list1  = (int*)carve((size_t)N * 4);
    int*    list2  = (int*)carve((size_t)N * 4);
    int*    col    = (int*)carve((size_t)E * 4);
    ushort* W1t    = (ushort*)carve((size_t)256 * 128 * 2);
    ushort* W2t    = (ushort*)carve((size_t)256 * 256 * 2);
    ushort* RA     = (ushort*)carve((size_t)N * H * 2);  // aggXc, then agg1c
    ushort* RB     = (ushort*)carve((size_t)N * H * 2);  // h1c, then h2c

    ushort* aggXc = RA;   // [M2][128]
    ushort* agg1c = RA;   // [M1][256] (aggXc dead after gemm1)
    ushort* h1c   = RB;   // [M2][256]
    ushort* h2c   = RB;   // [M1][256] (h1c dead after agg2)

    int nb = (N + 1023) / 1024;
    int e4 = (E + 3) / 4;
    int epN = (e4 > N ? e4 : N);

    // 1) zero counters/flags/slots
    hipMemsetAsync(cnt, 0, (size_t)(zend - (char*)cnt), stream);
    // 2) degrees + frontier1 + root pick (roots inline from batch)
    count_f1<<<(epN + 255) / 256, 256, 0, stream>>>(srcp, dstp, batch, cnt, flag1, picked, E, N);
    // 3) frontier2
    frontier2v<<<(epN + 255) / 256, 256, 0, stream>>>(srcp, dstp, flag1, flag2, E, N);
    // 4) single-kernel triple scan (+dis +wtrans)
    scan_one<<<nb, 256, 0, stream>>>(cnt, flag1, flag2, aggslot, dis, rowptr, cur,
                                     pos1, pos2, list1, list2, counts, N, nb,
                                     W1, W1t, W2, W2t);
    // 5) filtered CSR fill
    fill_fv<<<(e4 + 255) / 256, 256, 0, stream>>>(srcp, dstp, flag2, cur, col, E);
    // 6) layer-1 aggregation on S2
    aggx_c<<<1024, 256, 0, stream>>>(x, dis, rowptr, col, list2, counts, aggXc);
    // 7) layer-1 GEMM
    gemm_c<128><<<64, 512, 0, stream>>>(aggXc, W1t, b1, dis, list2, counts, 1, h1c);
    // 8) layer-2 aggregation on S1
    agg2_c<<<128, 256, 0, stream>>>(h1c, dis, rowptr, col, list1, pos2, counts, agg1c);
    // 9) layer-2 GEMM
    gemm_c<256><<<64, 512, 0, stream>>>(agg1c, W2t, b2, dis, list1, counts, 0, h2c);
    // 10) final at roots
    final_c<<<G, 256, 0, stream>>>(h2c, dis, rowptr, col, picked, pos1, W3, b3, (float*)d_out, G);
}

// Round 15
// 131.616 us; speedup vs baseline: 1.2783x; 1.0213x over previous
//
#include <hip/hip_runtime.h>

#define NEG_SLOPE 0.01f

using short8 = __attribute__((ext_vector_type(8))) short;
using f32x4  = __attribute__((ext_vector_type(4))) float;

__device__ inline float b2f(ushort u) {
    union { unsigned u; float f; } x; x.u = ((unsigned)u) << 16; return x.f;
}
__device__ inline ushort f2b(float f) {
    union { float f; unsigned u; } x; x.f = f;
    unsigned r = x.u + 0x7FFFu + ((x.u >> 16) & 1u);  // RNE
    return (ushort)(r >> 16);
}
__device__ inline void gload16(const void* g, void* l) {
    __builtin_amdgcn_global_load_lds((__attribute__((address_space(1))) void*)g,
                                     (__attribute__((address_space(3))) void*)l, 16, 0, 0);
}

// ---------------- init: zero flags/counters/scan-slots, mark roots, pick roots ----------------

__global__ void init_kernel(const int* __restrict__ batch, int* __restrict__ cnt,
                            int* __restrict__ flag1, int* __restrict__ flag2,
                            int* __restrict__ rootflag, int* __restrict__ picked,
                            int4* __restrict__ aggslot, int N) {
    int i = blockIdx.x * blockDim.x + threadIdx.x;
    if (i < 1024) aggslot[i] = make_int4(0, 0, 0, 0);
    if (i >= N) return;
    cnt[i] = 0;
    int root = (i == 0) || (batch[i] != batch[i - 1]);
    flag1[i] = root;   // roots are in S1
    flag2[i] = 0;
    rootflag[i] = root;
    if (root) picked[batch[i]] = i;
}

// ---------------- E-pass 1: degree count + frontier1 (flag1 |= src of root-dst edges) ----------------

__global__ void count_f1(const int* __restrict__ src, const int* __restrict__ dst,
                         const int* __restrict__ rootflag, int* __restrict__ cnt,
                         int* __restrict__ flag1, int E) {
    int i = blockIdx.x * blockDim.x + threadIdx.x;
    int e0 = i * 4;
    if (e0 + 3 < E) {
        int4 dq = *(const int4*)(dst + e0);
        int r0 = rootflag[dq.x], r1 = rootflag[dq.y], r2 = rootflag[dq.z], r3 = rootflag[dq.w];
        atomicAdd(&cnt[dq.x], 1);
        atomicAdd(&cnt[dq.y], 1);
        atomicAdd(&cnt[dq.z], 1);
        atomicAdd(&cnt[dq.w], 1);
        if (r0 | r1 | r2 | r3) {
            int4 sq = *(const int4*)(src + e0);
            if (r0) flag1[sq.x] = 1;
            if (r1) flag1[sq.y] = 1;
            if (r2) flag1[sq.z] = 1;
            if (r3) flag1[sq.w] = 1;
        }
    } else if (e0 < E) {
        for (int e = e0; e < E; e++) {
            int d = dst[e];
            atomicAdd(&cnt[d], 1);
            if (rootflag[d]) flag1[src[e]] = 1;
        }
    }
}

// ---------------- E-pass 2: frontier2 (flag2 = S1 U {src : dst in S1}) ----------------

__global__ void frontier2v(const int* __restrict__ src, const int* __restrict__ dst,
                           const int* __restrict__ flag1, int* __restrict__ flag2,
                           int E, int N) {
    int i = blockIdx.x * blockDim.x + threadIdx.x;
    int e0 = i * 4;
    if (e0 + 3 < E) {
        int4 dq = *(const int4*)(dst + e0);
        int f0 = flag1[dq.x], f1 = flag1[dq.y], f2 = flag1[dq.z], f3 = flag1[dq.w];
        if (f0 | f1 | f2 | f3) {
            int4 sq = *(const int4*)(src + e0);
            if (f0) flag2[sq.x] = 1;
            if (f1) flag2[sq.y] = 1;
            if (f2) flag2[sq.z] = 1;
            if (f3) flag2[sq.w] = 1;
        }
    } else if (e0 < E) {
        for (int e = e0; e < E; e++) if (flag1[dst[e]]) flag2[src[e]] = 1;
    }
    if (i < N && flag1[i]) flag2[i] = 1;
}

// ---------------- single-kernel triple scan (all-predecessor wave-parallel lookback) ----------------

__global__ __launch_bounds__(256) void scan_one(
    const int* __restrict__ cnt, const int* __restrict__ f1, const int* __restrict__ f2,
    int4* __restrict__ aggslot, float* __restrict__ dis,
    int* __restrict__ rowptr, int* __restrict__ cur,
    int* __restrict__ pos1, int* __restrict__ pos2,
    int* __restrict__ list1, int* __restrict__ list2,
    int* __restrict__ counts, int N, int nb,
    const float* __restrict__ W1, ushort* __restrict__ W1t,
    const float* __restrict__ W2, ushort* __restrict__ W2t) {
    __shared__ int l0[256], l1[256], l2[256];
    __shared__ int baseS[3];
    const int b = blockIdx.x, t = threadIdx.x;
    const int base = b * 1024 + t * 4;

    int c[4] = {0,0,0,0}, a1[4] = {0,0,0,0}, a2[4] = {0,0,0,0};
    if (base + 3 < N) {
        int4 q = *(const int4*)(cnt + base); c[0]=q.x; c[1]=q.y; c[2]=q.z; c[3]=q.w;
        int4 u = *(const int4*)(f1 + base);  a1[0]=u.x; a1[1]=u.y; a1[2]=u.z; a1[3]=u.w;
        int4 v = *(const int4*)(f2 + base);  a2[0]=v.x; a2[1]=v.y; a2[2]=v.z; a2[3]=v.w;
    } else {
        for (int i = 0; i < 4; i++) if (base + i < N) {
            c[i] = cnt[base + i]; a1[i] = f1[base + i]; a2[i] = f2[base + i];
        }
    }
#pragma unroll
    for (int i = 0; i < 4; i++)
        if (base + i < N) dis[base + i] = rsqrtf((float)c[i] + 1.0f);

    int m[4];
#pragma unroll
    for (int i = 0; i < 4; i++) m[i] = a2[i] ? c[i] : 0;
    int ts0 = m[0] + m[1] + m[2] + m[3];
    int ts1 = a1[0] + a1[1] + a1[2] + a1[3];
    int ts2 = a2[0] + a2[1] + a2[2] + a2[3];
    l0[t] = ts0; l1[t] = ts1; l2[t] = ts2;
    __syncthreads();
    for (int off = 1; off < 256; off <<= 1) {
        int u0 = (t >= off) ? l0[t - off] : 0;
        int u1 = (t >= off) ? l1[t - off] : 0;
        int u2 = (t >= off) ? l2[t - off] : 0;
        __syncthreads();
        l0[t] += u0; l1[t] += u1; l2[t] += u2;
        __syncthreads();
    }

    if (t == 0) {
        __hip_atomic_store(&aggslot[b].x, l0[255], __ATOMIC_RELAXED, __HIP_MEMORY_SCOPE_AGENT);
        __hip_atomic_store(&aggslot[b].y, l1[255], __ATOMIC_RELAXED, __HIP_MEMORY_SCOPE_AGENT);
        __hip_atomic_store(&aggslot[b].z, l2[255], __ATOMIC_RELAXED, __HIP_MEMORY_SCOPE_AGENT);
        __hip_atomic_store(&aggslot[b].w, 1, __ATOMIC_RELEASE, __HIP_MEMORY_SCOPE_AGENT);
    }

    if (t < 64) {
        int g0 = 0, g1 = 0, g2 = 0;
        for (int w0 = 0; w0 < b; w0 += 64) {
            int idx = w0 + t;
            if (idx < b) {
                while (__hip_atomic_load(&aggslot[idx].w, __ATOMIC_ACQUIRE,
                                         __HIP_MEMORY_SCOPE_AGENT) == 0) {
                    __builtin_amdgcn_s_sleep(1);
                }
                g0 += __hip_atomic_load(&aggslot[idx].x, __ATOMIC_RELAXED, __HIP_MEMORY_SCOPE_AGENT);
                g1 += __hip_atomic_load(&aggslot[idx].y, __ATOMIC_RELAXED, __HIP_MEMORY_SCOPE_AGENT);
                g2 += __hip_atomic_load(&aggslot[idx].z, __ATOMIC_RELAXED, __HIP_MEMORY_SCOPE_AGENT);
            }
        }
#pragma unroll
        for (int s = 1; s < 64; s <<= 1) {
            g0 += __shfl_xor(g0, s, 64);
            g1 += __shfl_xor(g1, s, 64);
            g2 += __shfl_xor(g2, s, 64);
        }
        if (t == 0) { baseS[0] = g0; baseS[1] = g1; baseS[2] = g2; }
    }
    __syncthreads();

    int run0 = baseS[0] + l0[t] - ts0;
    int run1 = baseS[1] + l1[t] - ts1;
    int run2 = baseS[2] + l2[t] - ts2;
#pragma unroll
    for (int i = 0; i < 4; i++) {
        if (base + i < N) {
            rowptr[base + i] = run0;
            cur[base + i] = run0;
            if (a1[i]) { pos1[base + i] = run1; list1[run1] = base + i; }
            if (a2[i]) { pos2[base + i] = run2; list2[run2] = base + i; }
        }
        run0 += m[i]; run1 += a1[i]; run2 += a2[i];
    }
    if (b == nb - 1 && t == 255) {
        counts[0] = baseS[1] + l1[255];   // M1
        counts[1] = baseS[2] + l2[255];   // M2
        rowptr[N] = baseS[0] + l0[255];   // total kept edges
    }

    // fused weight transposes
    for (int idx = b * 256 + t; idx < 98304; idx += gridDim.x * 256) {
        if (idx < 32768) {                   // W1t[n][k] = W1[k][n], K=128
            int n = idx >> 7, k = idx & 127;
            W1t[idx] = f2b(W1[k * 256 + n]);
        } else {                             // W2t[n][k] = W2[k][n], K=256
            int j = idx - 32768;
            int n = j >> 8, k = j & 255;
            W2t[j] = f2b(W2[k * 256 + n]);
        }
    }
}

// ---------------- E-pass 3: filtered CSR fill (only edges whose dst is in S2) ----------------

__global__ void fill_fv(const int* __restrict__ src, const int* __restrict__ dst,
                        const int* __restrict__ flag2, int* __restrict__ cur,
                        int* __restrict__ col, int E) {
    int i = blockIdx.x * blockDim.x + threadIdx.x;
    int e0 = i * 4;
    if (e0 + 3 < E) {
        int4 dq = *(const int4*)(dst + e0);
        int f0 = flag2[dq.x], f1 = flag2[dq.y], f2 = flag2[dq.z], f3 = flag2[dq.w];
        if (f0 | f1 | f2 | f3) {
            int4 sq = *(const int4*)(src + e0);
            if (f0) col[atomicAdd(&cur[dq.x], 1)] = sq.x;
            if (f1) col[atomicAdd(&cur[dq.y], 1)] = sq.y;
            if (f2) col[atomicAdd(&cur[dq.z], 1)] = sq.z;
            if (f3) col[atomicAdd(&cur[dq.w], 1)] = sq.w;
        }
    } else if (e0 < E) {
        for (int e = e0; e < E; e++) {
            int d = dst[e];
            if (flag2[d]) col[atomicAdd(&cur[d], 1)] = src[e];
        }
    }
}

// ---------------- layer-1 aggregation on S2 (compact): from f32 x directly ----------------

__global__ __launch_bounds__(256) void aggx_c(const float* __restrict__ x,
                                              const float* __restrict__ dis,
                                              const int* __restrict__ rowptr,
                                              const int* __restrict__ col,
                                              const int* __restrict__ list2,
                                              const int* __restrict__ counts,
                                              ushort* __restrict__ aggXc) {
    const int M2 = counts[1];
    int wave = blockIdx.x * 4 + (threadIdx.x >> 6);
    int lane = threadIdx.x & 63;
    int li = lane & 31, sub = lane >> 5;
    int stride = gridDim.x * 8;
    const float* xp = x + li * 4;
    for (int p = wave * 2 + sub; p < M2; p += stride) {
        int node = list2[p];
        float di = dis[node];
        float4 sv = *(const float4*)(xp + (size_t)node * 128);
        float a0 = di * sv.x, a1 = di * sv.y, a2 = di * sv.z, a3 = di * sv.w;
        int e = rowptr[node], e1 = rowptr[node + 1];
        for (; e + 2 <= e1; e += 2) {
            int s0 = col[e], s1 = col[e + 1];
            float w0 = dis[s0], w1 = dis[s1];
            float4 v0 = *(const float4*)(xp + (size_t)s0 * 128);
            float4 v1 = *(const float4*)(xp + (size_t)s1 * 128);
            a0 += w0 * v0.x + w1 * v1.x;
            a1 += w0 * v0.y + w1 * v1.y;
            a2 += w0 * v0.z + w1 * v1.z;
            a3 += w0 * v0.w + w1 * v1.w;
        }
        if (e < e1) {
            int s = col[e];
            float w = dis[s];
            float4 v = *(const float4*)(xp + (size_t)s * 128);
            a0 += w * v.x; a1 += w * v.y; a2 += w * v.z; a3 += w * v.w;
        }
        ushort4 o;
        o.x = f2b(di * a0); o.y = f2b(di * a1); o.z = f2b(di * a2); o.w = f2b(di * a3);
        *(ushort4*)(aggXc + (size_t)p * 128 + li * 4) = o;
    }
}

// ---------------- layer-2 aggregation on S1 (compact), h1c indexed via pos2 ----------------

__global__ __launch_bounds__(256) void agg2_c(const ushort* __restrict__ h1c,
                                              const float* __restrict__ dis,
                                              const int* __restrict__ rowptr,
                                              const int* __restrict__ col,
                                              const int* __restrict__ list1,
                                              const int* __restrict__ pos2,
                                              const int* __restrict__ counts,
                                              ushort* __restrict__ agg1c) {
    const int M1 = counts[0];
    int wave = blockIdx.x * 4 + (threadIdx.x >> 6);
    int lane = threadIdx.x & 63;
    int li = lane & 31, sub = lane >> 5;
    int stride = gridDim.x * 8;
    const ushort* hp = h1c + (size_t)li * 8;
    for (int p = wave * 2 + sub; p < M1; p += stride) {
        int i = list1[p];
        float di = dis[i];
        float a[8];
        {
            short8 v = *(const short8*)(hp + (size_t)pos2[i] * 256);
#pragma unroll
            for (int j = 0; j < 8; j++) a[j] = b2f((ushort)v[j]);
        }
        int e1 = rowptr[i + 1];
        for (int e = rowptr[i]; e < e1; e++) {
            short8 v = *(const short8*)(hp + (size_t)pos2[col[e]] * 256);
#pragma unroll
            for (int j = 0; j < 8; j++) a[j] += b2f((ushort)v[j]);
        }
        short8 o;
#pragma unroll
        for (int j = 0; j < 8; j++) o[j] = (short)f2b(di * a[j]);
        *(short8*)(agg1c + (size_t)p * 256 + li * 8) = o;
    }
}

// ---------------- compact MFMA GEMM: C[M x 256] = bf16( dis[list[row]] * leaky(A @ Bt^T + bias) ) ----------------

template <int K>
__global__ __launch_bounds__(512) void gemm_c(const ushort* __restrict__ A,
                                              const ushort* __restrict__ Bt,
                                              const float* __restrict__ bias,
                                              const float* __restrict__ dis,
                                              const int* __restrict__ list,
                                              const int* __restrict__ counts, int which,
                                              ushort* __restrict__ C) {
    __shared__ ushort As[128 * 64];   // 16 KB
    __shared__ ushort Bs[256 * 64];   // 32 KB
    const int M = counts[which];
    const int t = threadIdx.x;
    const int lane = t & 63;
    const int w = t >> 6;
    const int wm = w >> 2, wn = w & 3;

    for (int tile = blockIdx.x; tile * 128 < M; tile += gridDim.x) {
        const int row0 = tile * 128;
        f32x4 acc[4][4] = {};

        for (int kt = 0; kt < K / 64; kt++) {
#pragma unroll
            for (int it = 0; it < 2; it++) {
                int q = it * 512 + t;
                int r = q >> 3, c = q & 7;
                int cs = c ^ (r & 7);
                int ga = min(row0 + r, M - 1);
                gload16(A + (size_t)ga * K + kt * 64 + cs * 8, &As[q * 8]);
            }
#pragma unroll
            for (int it = 0; it < 4; it++) {
                int q = it * 512 + t;
                int r = q >> 3, c = q & 7;
                int cs = c ^ (r & 7);
                gload16(Bt + (size_t)r * K + kt * 64 + cs * 8, &Bs[q * 8]);
            }
            __syncthreads();
#pragma unroll
            for (int ks = 0; ks < 2; ks++) {
                short8 a[4], b[4];
                int cc = ks * 4 + (lane >> 4);
#pragma unroll
                for (int m = 0; m < 4; m++) {
                    int R = wm * 64 + m * 16 + (lane & 15);
                    a[m] = *(const short8*)&As[R * 64 + ((cc ^ (R & 7)) * 8)];
                }
#pragma unroll
                for (int n = 0; n < 4; n++) {
                    int R = wn * 64 + n * 16 + (lane & 15);
                    b[n] = *(const short8*)&Bs[R * 64 + ((cc ^ (R & 7)) * 8)];
                }
#pragma unroll
                for (int m = 0; m < 4; m++)
#pragma unroll
                    for (int n = 0; n < 4; n++)
                        acc[m][n] = __builtin_amdgcn_mfma_f32_16x16x32_bf16(a[m], b[n], acc[m][n], 0, 0, 0);
            }
            __syncthreads();
        }

#pragma unroll
        for (int m = 0; m < 4; m++) {
#pragma unroll
            for (int j = 0; j < 4; j++) {
                int grow = row0 + wm * 64 + m * 16 + (lane >> 4) * 4 + j;
                if (grow >= M) continue;
                float dr = dis[list[grow]];
#pragma unroll
                for (int n = 0; n < 4; n++) {
                    int gcol = wn * 64 + n * 16 + (lane & 15);
                    float v = acc[m][n][j] + bias[gcol];
                    v = v > 0.f ? v : NEG_SLOPE * v;
                    C[(size_t)grow * 256 + gcol] = f2b(v * dr);
                }
            }
        }
    }
}

// ---------------- final: per graph, aggregate h2c at the root (via pos1), then 256x16 GEMM ----------------

__global__ __launch_bounds__(256) void final_c(const ushort* __restrict__ h2c,
                                               const float* __restrict__ dis,
                                               const int* __restrict__ rowptr,
                                               const int* __restrict__ col,
                                               const int* __restrict__ picked,
                                               const int* __restrict__ pos1,
                                               const float* __restrict__ W3,
                                               const float* __restrict__ b3,
                                               float* __restrict__ out, int G) {
    __shared__ float agg[256];
    __shared__ float red[256];
    int g = blockIdx.x;
    int t = threadIdx.x;
    if (g >= G) return;
    int i = picked[g];
    float di = dis[i];
    float a = b2f(h2c[(size_t)pos1[i] * 256 + t]);
    int e1 = rowptr[i + 1];
    for (int e = rowptr[i]; e < e1; e++) {
        a += b2f(h2c[(size_t)pos1[col[e]] * 256 + t]);
    }
    agg[t] = di * a;
    __syncthreads();
    int c = t & 15, seg = t >> 4;
    float p = 0.f;
#pragma unroll
    for (int kk = 0; kk < 16; kk++) {
        int k = seg * 16 + kk;
        p += agg[k] * W3[k * 16 + c];
    }
    red[t] = p;
    __syncthreads();
    if (t < 16) {
        float sres = 0.f;
#pragma unroll
        for (int ss = 0; ss < 16; ss++) sres += red[ss * 16 + t];
        out[g * 16 + t] = sres + b3[t];
    }
}

// ---------------- launch ----------------

extern "C" void kernel_launch(void* const* d_in, const int* in_sizes, int n_in,
                              void* d_out, int out_size, void* d_ws, size_t ws_size,
                              hipStream_t stream) {
    const float* x   = (const float*)d_in[0];
    const int* ei    = (const int*)d_in[1];
    const int* batch = (const int*)d_in[2];
    const float* W1  = (const float*)d_in[3];
    const float* b1  = (const float*)d_in[4];
    const float* W2  = (const float*)d_in[5];
    const float* b2  = (const float*)d_in[6];
    const float* W3  = (const float*)d_in[7];
    const float* b3  = (const float*)d_in[8];

    const int IN = 128, H = 256, OUT = 16;
    int N = in_sizes[0] / IN;
    int E = in_sizes[1] / 2;
    int G = out_size / OUT;
    const int* srcp = ei;
    const int* dstp = ei + E;

    char* p = (char*)d_ws;
    auto carve = [&](size_t bytes) {
        char* q = p;
        p += (bytes + 255) & ~(size_t)255;
        return q;
    };
    int*    cnt      = (int*)carve((size_t)N * 4);
    int*    flag1    = (int*)carve((size_t)N * 4);
    int*    flag2    = (int*)carve((size_t)N * 4);
    int*    rootflag = (int*)carve((size_t)N * 4);
    float*  dis    = (float*)carve((size_t)N * 4);
    int*    rowptr = (int*)carve(((size_t)N + 1) * 4);
    int*    cur    = (int*)carve((size_t)N * 4);
    int4*   aggslot= (int4*)carve(1024 * 16);
    int*    counts = (int*)carve(256);
    int*    picked = (int*)carve((size_t)G * 4);
    int*    pos1   = (int*)carve((size_t)N * 4);
    int*    pos2   = (int*)carve((size_t)N * 4);
    int*    list1  = (int*)carve((size_t)N * 4);
    int*    list2  = (int*)carve((size_t)N * 4);
    int*    col    = (int*)carve((size_t)E * 4);
    ushort* W1t    = (ushort*)carve((size_t)256 * 128 * 2);
    ushort* W2t    = (ushort*)carve((size_t)256 * 256 * 2);
    ushort* RA     = (ushort*)carve((size_t)N * H * 2);  // aggXc, then agg1c
    ushort* RB     = (ushort*)carve((size_t)N * H * 2);  // h1c, then h2c

    ushort* aggXc = RA;   // [M2][128]
    ushort* agg1c = RA;   // [M1][256] (aggXc dead after gemm1)
    ushort* h1c   = RB;   // [M2][256]
    ushort* h2c   = RB;   // [M1][256] (h1c dead after agg2)

    int nb = (N + 1023) / 1024;
    int e4 = (E + 3) / 4;
    int epN = (e4 > N ? e4 : N);

    // 1) init
    init_kernel<<<(N + 255) / 256, 256, 0, stream>>>(batch, cnt, flag1, flag2, rootflag,
                                                     picked, aggslot, N);
    // 2) degrees + frontier1
    count_f1<<<(e4 + 255) / 256, 256, 0, stream>>>(srcp, dstp, rootflag, cnt, flag1, E);
    // 3) frontier2
    frontier2v<<<(epN + 255) / 256, 256, 0, stream>>>(srcp, dstp, flag1, flag2, E, N);
    // 4) single-kernel triple scan (+dis +wtrans)
    scan_one<<<nb, 256, 0, stream>>>(cnt, flag1, flag2, aggslot, dis, rowptr, cur,
                                     pos1, pos2, list1, list2, counts, N, nb,
                                     W1, W1t, W2, W2t);
    // 5) filtered CSR fill
    fill_fv<<<(e4 + 255) / 256, 256, 0, stream>>>(srcp, dstp, flag2, cur, col, E);
    // 6) layer-1 aggregation on S2
    aggx_c<<<1024, 256, 0, stream>>>(x, dis, rowptr, col, list2, counts, aggXc);
    // 7) layer-1 GEMM
    gemm_c<128><<<128, 512, 0, stream>>>(aggXc, W1t, b1, dis, list2, counts, 1, h1c);
    // 8) layer-2 aggregation on S1
    agg2_c<<<128, 256, 0, stream>>>(h1c, dis, rowptr, col, list1, pos2, counts, agg1c);
    // 9) layer-2 GEMM
    gemm_c<256><<<64, 512, 0, stream>>>(agg1c, W2t, b2, dis, list1, counts, 0, h2c);
    // 10) final at roots
    final_c<<<G, 256, 0, stream>>>(h2c, dis, rowptr, col, picked, pos1, W3, b3, (float*)d_out, G);
}